// Round 6
// baseline (131.780 us; speedup 1.0000x reference)
//
#include <hip/hip_runtime.h>
#include <hip/hip_cooperative_groups.h>

namespace cg = cooperative_groups;

#define CH    512
#define BATCH 16
#define NB    1024     // cooperative grid: 4 blocks/CU * 256 CUs
#define QB    8        // batches per phase-1 block
#define NQ    2        // BATCH / QB
#define HW    3136     // 56*56
#define HW4   784      // HW/4
#define THRESH 8.0f
#define MAXR  3072     // LDS plan-table capacity (actual R ~ 1030)

typedef float f4 __attribute__((ext_vector_type(4)));

__global__ __launch_bounds__(256, 4) void fused_kernel(
        const float* __restrict__ x,
        float*       __restrict__ partial,
        float*       __restrict__ out,
        float*       __restrict__ out_tail,
        int R) {
    const int g   = blockIdx.x;
    const int tid = threadIdx.x;
    const int lane = tid & 63;
    const int w    = tid >> 6;

    // ---- phase 1: max|x| over 8 planes of channel c, batch half q -------
    {
        const int c = g >> 1, q = g & 1;
        float m = 0.0f;
        for (int bb = 0; bb < QB; ++bb) {
            const int b = q * QB + bb;
            const f4* src = reinterpret_cast<const f4*>(x) + (size_t)(b * CH + c) * HW4;
            for (int p = tid; p < HW4; p += 256) {
                f4 v = src[p];
                m = fmaxf(m, fmaxf(fmaxf(fabsf(v.x), fabsf(v.y)),
                                   fmaxf(fabsf(v.z), fabsf(v.w))));
            }
        }
        __shared__ float sm[256];
        sm[tid] = m;
        __syncthreads();
        for (int off = 128; off > 0; off >>= 1) {
            if (tid < off) sm[tid] = fmaxf(sm[tid], sm[tid + off]);
            __syncthreads();
        }
        if (tid == 0) partial[(c << 1) + q] = sm[0];
    }

    cg::this_grid().sync();

    // ---- phase 2a: every block rebuilds the plan into LDS ---------------
    // thread t owns channels c0=2t, c1=2t+1; partial f4 = {c0q0,c0q1,c1q0,c1q1}
    __shared__ unsigned short rep_c[MAXR];
    __shared__ unsigned char  rep_T[MAXR];
    __shared__ int wsum[4];

    const int c0 = tid * 2, c1 = c0 + 1;
    f4 pp = reinterpret_cast<const f4*>(partial)[tid];
    float m0 = fmaxf(pp.x, pp.y);
    float m1 = fmaxf(pp.z, pp.w);
    int T0 = (m0 > THRESH) ? (int)ceilf(m0 * 0.125f) : 0;  // ceil(m/8) exact
    int T1 = (m1 > THRESH) ? (int)ceilf(m1 * 0.125f) : 0;
    const int v = T0 + T1;

    int s = v;                                  // wave-inclusive scan
    #pragma unroll
    for (int off = 1; off < 64; off <<= 1) {
        int t2 = __shfl_up(s, off, 64);
        if (lane >= off) s += t2;
    }
    if (lane == 63) wsum[w] = s;
    __syncthreads();
    int woff = 0;
    #pragma unroll
    for (int k = 0; k < 4; ++k) if (k < w) woff += wsum[k];
    const int start0 = woff + s - v;            // first slot of channel c0
    const int start1 = start0 + T0;
    for (int k = 0; k < T0; ++k) { rep_c[start0 + k] = (unsigned short)c0; rep_T[start0 + k] = (unsigned char)T0; }
    for (int k = 0; k < T1; ++k) { rep_c[start1 + k] = (unsigned short)c1; rep_T[start1 + k] = (unsigned char)T1; }

    // block 0 writes the outlier-id tail (fp32 channel ids, ordinal order)
    if (g == 0) {
        __shared__ int wsum2[4];
        const int o0 = (T0 > 0), o1 = (T1 > 0);
        const int v2 = o0 + o1;
        int s2 = v2;
        #pragma unroll
        for (int off = 1; off < 64; off <<= 1) {
            int t2 = __shfl_up(s2, off, 64);
            if (lane >= off) s2 += t2;
        }
        if (lane == 63) wsum2[w] = s2;
        __syncthreads();
        int woff2 = 0;
        #pragma unroll
        for (int k = 0; k < 4; ++k) if (k < w) woff2 += wsum2[k];
        const int ex2 = woff2 + s2 - v2;
        if (o0) out_tail[ex2]      = (float)c0;
        if (o1) out_tail[ex2 + o0] = (float)c1;
    }
    __syncthreads();

    // ---- phase 2b: gather + scale + NT store, 16 units per block --------
    // unit u -> (j = u>>4, b = u&15); replicas of one plane land on blocks
    // g, g+16 (same XCD mod 8) running concurrently -> L2-shared reads.
    const int total = R * BATCH;
    for (int u = g; u < total; u += NB) {
        const int j = u >> 4;
        const int b = u & 15;
        const int   c  = rep_c[j];
        const int   T  = rep_T[j];
        const float sc = (float)(1.0 / (double)T);   // numpy f64->f32 rounding
        const f4* src = reinterpret_cast<const f4*>(x)   + (size_t)(b * CH + c) * HW4;
        f4*       dst = reinterpret_cast<f4*>(out)       + ((size_t)b * R + j) * HW4;
        for (int p = tid; p < HW4; p += 256) {
            f4 vv = src[p];
            vv.x *= sc; vv.y *= sc; vv.z *= sc; vv.w *= sc;
            __builtin_nontemporal_store(vv, &dst[p]);   // never re-read
        }
    }
}

extern "C" void kernel_launch(void* const* d_in, const int* in_sizes, int n_in,
                              void* d_out, int out_size, void* d_ws, size_t ws_size,
                              hipStream_t stream) {
    const float* x = (const float*)d_in[0];
    float* out = (float*)d_out;

    // out_size = 50176*R + n_out,  n_out <= 512 < 50176  -> unique split
    const int plane = BATCH * HW;               // 50176
    int R = out_size / plane;                   // total replicated channels

    float* partial  = (float*)d_ws;             // CH*NQ = 1024 floats
    float* out_tail = out + (size_t)R * plane;

    void* args[] = { (void*)&x, (void*)&partial, (void*)&out, (void*)&out_tail, (void*)&R };
    hipLaunchCooperativeKernel(reinterpret_cast<void*>(fused_kernel),
                               dim3(NB), dim3(256), args, 0, stream);
}

// Round 7
// 69.202 us; speedup vs baseline: 1.9043x; 1.9043x over previous
//
#include <hip/hip_runtime.h>

#define CH    512
#define BATCH 16
#define QB    4        // batch planes per absmax block
#define NQ    (BATCH / QB)
#define HW    3136     // 56*56
#define HW4   784      // HW/4 (float4 per image plane)
#define THRESH 8.0f

typedef float f4 __attribute__((ext_vector_type(4)));

// ---- Kernel 1: partial[c*NQ+q] = max|x[b in q*QB..q*QB+3, c, :, :]| -----
__global__ __launch_bounds__(256) void absmax_kernel(const float* __restrict__ x,
                                                     float* __restrict__ partial) {
    const int c   = blockIdx.x;
    const int q   = blockIdx.y;
    const int tid = threadIdx.x;
    float m = 0.0f;
    for (int bb = 0; bb < QB; ++bb) {
        const int b = q * QB + bb;
        const f4* src = reinterpret_cast<const f4*>(x) + (size_t)(b * CH + c) * HW4;
        for (int p = tid; p < HW4; p += 256) {
            f4 v = src[p];
            m = fmaxf(m, fmaxf(fmaxf(fabsf(v.x), fabsf(v.y)),
                               fmaxf(fabsf(v.z), fabsf(v.w))));
        }
    }
    __shared__ float sm[256];
    sm[tid] = m;
    __syncthreads();
    for (int off = 128; off > 0; off >>= 1) {
        if (tid < off) sm[tid] = fmaxf(sm[tid], sm[tid + off]);
        __syncthreads();
    }
    if (tid == 0) partial[c * NQ + q] = sm[0];
}

// ---- Kernel 2: gather + scale; each block recomputes the plan locally ---
__global__ __launch_bounds__(256) void gather_kernel(const float* __restrict__ x,
                                                     const float* __restrict__ partial,
                                                     float* __restrict__ out,
                                                     float* __restrict__ out_tail,
                                                     int R) {
    // bijective XCD chunk mapping (8 XCDs): neighbor output channels stay on
    // the same XCD so replica re-reads hit that XCD's L2.
    const int nwg  = gridDim.x;
    const int orig = blockIdx.x;
    const int xcd  = orig & 7;
    const int q8 = nwg >> 3, r8 = nwg & 7;
    const int wg = (xcd < r8 ? xcd * (q8 + 1) : r8 * (q8 + 1) + (xcd - r8) * q8)
                   + (orig >> 3);
    const int j = wg >> 4;        // output channel slot (BATCH = 16)
    const int b = wg & 15;        // batch

    const int tid  = threadIdx.x;
    const int lane = tid & 63;
    const int w    = tid >> 6;    // wave id (4 waves)

    // --- local plan: thread t owns channels c0=2t, c1=2t+1 ---------------
    const int c0 = tid * 2, c1 = c0 + 1;
    f4 p0 = reinterpret_cast<const f4*>(partial)[tid * 2];      // c0's 4 partials
    f4 p1 = reinterpret_cast<const f4*>(partial)[tid * 2 + 1];  // c1's 4 partials
    float m0 = fmaxf(fmaxf(p0.x, p0.y), fmaxf(p0.z, p0.w));
    float m1 = fmaxf(fmaxf(p1.x, p1.y), fmaxf(p1.z, p1.w));
    int T0 = (m0 > THRESH) ? (int)ceilf(m0 * 0.125f) : 0;  // ceil(m/8), exact
    int T1 = (m1 > THRESH) ? (int)ceilf(m1 * 0.125f) : 0;
    const int v = T0 + T1;

    // wave-inclusive scan of v over 64 lanes (no barriers)
    int s = v;
    #pragma unroll
    for (int off = 1; off < 64; off <<= 1) {
        int t2 = __shfl_up(s, off, 64);
        if (lane >= off) s += t2;
    }
    __shared__ int wsum[4];
    if (lane == 63) wsum[w] = s;
    __syncthreads();
    int woff = 0;
    #pragma unroll
    for (int k = 0; k < 4; ++k) if (k < w) woff += wsum[k];
    const int excl   = woff + s - v;       // first output slot of channel c0
    const int start0 = excl, start1 = excl + T0;

    __shared__ int sc, sT;
    if (T0 > 0 && j >= start0 && j < start0 + T0) { sc = c0; sT = T0; }
    if (T1 > 0 && j >= start1 && j < start1 + T1) { sc = c1; sT = T1; }

    // block wg==0 additionally writes the outlier-id tail (fp32 channel ids)
    if (wg == 0) {
        const int o0 = (T0 > 0), o1 = (T1 > 0);
        const int v2 = o0 + o1;
        int s2 = v2;
        #pragma unroll
        for (int off = 1; off < 64; off <<= 1) {
            int t2 = __shfl_up(s2, off, 64);
            if (lane >= off) s2 += t2;
        }
        __shared__ int wsum2[4];
        if (lane == 63) wsum2[w] = s2;
        __syncthreads();
        int woff2 = 0;
        #pragma unroll
        for (int k = 0; k < 4; ++k) if (k < w) woff2 += wsum2[k];
        const int ex2 = woff2 + s2 - v2;
        if (o0) out_tail[ex2]      = (float)c0;
        if (o1) out_tail[ex2 + o0] = (float)c1;
    }
    __syncthreads();

    const int   c     = sc;                          // wave-uniform
    const float scale = (float)(1.0 / (double)sT);   // numpy f64->f32 rounding

    const f4* src = reinterpret_cast<const f4*>(x) + (size_t)(b * CH + c) * HW4;
    f4* dst = reinterpret_cast<f4*>(out) + ((size_t)b * R + j) * HW4;
    for (int p = tid; p < HW4; p += 256) {
        f4 vv = src[p];
        vv.x *= scale; vv.y *= scale; vv.z *= scale; vv.w *= scale;
        dst[p] = vv;                       // A/B vs R4: regular (non-NT) store
    }
}

extern "C" void kernel_launch(void* const* d_in, const int* in_sizes, int n_in,
                              void* d_out, int out_size, void* d_ws, size_t ws_size,
                              hipStream_t stream) {
    const float* x = (const float*)d_in[0];
    float* out = (float*)d_out;

    // out_size = 50176*R + n_out,  n_out <= 512 < 50176  -> unique split
    const int plane = BATCH * HW;               // 50176
    const int R     = out_size / plane;         // total replicated channels

    float* partial = (float*)d_ws;              // CH*NQ floats (8 KB)

    absmax_kernel<<<dim3(CH, NQ), 256, 0, stream>>>(x, partial);
    if (R > 0) {
        gather_kernel<<<dim3(R * BATCH), 256, 0, stream>>>(
            x, partial, out, out + (size_t)R * plane, R);
    }
}

// Round 8
// 65.365 us; speedup vs baseline: 2.0161x; 1.0587x over previous
//
#include <hip/hip_runtime.h>

#define CH    512
#define BATCH 16
#define QB    4        // batch planes per absmax block
#define NQ    (BATCH / QB)
#define HW    3136     // 56*56
#define HW4   784      // HW/4 (float4 per image plane)
#define THRESH 8.0f

typedef float f4 __attribute__((ext_vector_type(4)));

// ---- Kernel 1: partial[c*NQ+q] = max|x[b in q*QB.., c, :, :]| -----------
__global__ __launch_bounds__(256) void absmax_kernel(const float* __restrict__ x,
                                                     float* __restrict__ partial) {
    const int c   = blockIdx.x;
    const int q   = blockIdx.y;
    const int tid = threadIdx.x;
    float m = 0.0f;
    for (int bb = 0; bb < QB; ++bb) {
        const int b = q * QB + bb;
        const f4* src = reinterpret_cast<const f4*>(x) + (size_t)(b * CH + c) * HW4;
        for (int p = tid; p < HW4; p += 256) {
            f4 v = src[p];
            m = fmaxf(m, fmaxf(fmaxf(fabsf(v.x), fabsf(v.y)),
                               fmaxf(fabsf(v.z), fabsf(v.w))));
        }
    }
    __shared__ float sm[256];
    sm[tid] = m;
    __syncthreads();
    for (int off = 128; off > 0; off >>= 1) {
        if (tid < off) sm[tid] = fmaxf(sm[tid], sm[tid + off]);
        __syncthreads();
    }
    if (tid == 0) partial[c * NQ + q] = sm[0];
}

// ---- Kernel 2: one block per output channel j; streams all 16 batches ---
__global__ __launch_bounds__(256) void gather_kernel(const float* __restrict__ x,
                                                     const float* __restrict__ partial,
                                                     float* __restrict__ out,
                                                     float* __restrict__ out_tail,
                                                     int R) {
    // bijective XCD chunk mapping (8 XCDs): replica pairs (j, j+1) of one
    // source plane land in the same chunk -> same XCD -> L2-shared reads.
    const int nwg  = gridDim.x;
    const int orig = blockIdx.x;
    const int xcd  = orig & 7;
    const int q8 = nwg >> 3, r8 = nwg & 7;
    const int j = (xcd < r8 ? xcd * (q8 + 1) : r8 * (q8 + 1) + (xcd - r8) * q8)
                  + (orig >> 3);           // output channel slot

    const int tid  = threadIdx.x;
    const int lane = tid & 63;
    const int w    = tid >> 6;    // wave id (4 waves)

    // --- plan (once per block): thread t owns channels c0=2t, c1=2t+1 ----
    const int c0 = tid * 2, c1 = c0 + 1;
    f4 p0 = reinterpret_cast<const f4*>(partial)[tid * 2];
    f4 p1 = reinterpret_cast<const f4*>(partial)[tid * 2 + 1];
    float m0 = fmaxf(fmaxf(p0.x, p0.y), fmaxf(p0.z, p0.w));
    float m1 = fmaxf(fmaxf(p1.x, p1.y), fmaxf(p1.z, p1.w));
    int T0 = (m0 > THRESH) ? (int)ceilf(m0 * 0.125f) : 0;  // ceil(m/8), exact
    int T1 = (m1 > THRESH) ? (int)ceilf(m1 * 0.125f) : 0;
    const int v = T0 + T1;

    int s = v;                    // wave-inclusive scan (no barriers)
    #pragma unroll
    for (int off = 1; off < 64; off <<= 1) {
        int t2 = __shfl_up(s, off, 64);
        if (lane >= off) s += t2;
    }
    __shared__ int wsum[4];
    if (lane == 63) wsum[w] = s;
    __syncthreads();
    int woff = 0;
    #pragma unroll
    for (int k = 0; k < 4; ++k) if (k < w) woff += wsum[k];
    const int excl   = woff + s - v;       // first output slot of channel c0
    const int start0 = excl, start1 = excl + T0;

    __shared__ int sc, sT;
    if (T0 > 0 && j >= start0 && j < start0 + T0) { sc = c0; sT = T0; }
    if (T1 > 0 && j >= start1 && j < start1 + T1) { sc = c1; sT = T1; }

    // block j==0 additionally writes the outlier-id tail (fp32 channel ids)
    if (j == 0) {
        const int o0 = (T0 > 0), o1 = (T1 > 0);
        const int v2 = o0 + o1;
        int s2 = v2;
        #pragma unroll
        for (int off = 1; off < 64; off <<= 1) {
            int t2 = __shfl_up(s2, off, 64);
            if (lane >= off) s2 += t2;
        }
        __shared__ int wsum2[4];
        if (lane == 63) wsum2[w] = s2;
        __syncthreads();
        int woff2 = 0;
        #pragma unroll
        for (int k = 0; k < 4; ++k) if (k < w) woff2 += wsum2[k];
        const int ex2 = woff2 + s2 - v2;
        if (o0) out_tail[ex2]      = (float)c0;
        if (o1) out_tail[ex2 + o0] = (float)c1;
    }
    __syncthreads();

    const int   c     = sc;                          // block-uniform
    const float scale = (float)(1.0 / (double)sT);   // numpy f64->f32 rounding

    // stream all BATCH planes of channel c -> output slot j, flattened loop
    const f4* srcb = reinterpret_cast<const f4*>(x)   + (size_t)c * HW4;
    f4*       dstb = reinterpret_cast<f4*>(out)       + (size_t)j * HW4;
    for (int idx = tid; idx < BATCH * HW4; idx += 256) {
        const int b = idx / HW4;             // const-div -> magic mul
        f4 vv = srcb[(size_t)b * (CH * HW4 - HW4) + idx];
        vv.x *= scale; vv.y *= scale; vv.z *= scale; vv.w *= scale;
        __builtin_nontemporal_store(vv, &dstb[(size_t)b * ((size_t)(R - 1) * HW4) + idx]);
    }
}

extern "C" void kernel_launch(void* const* d_in, const int* in_sizes, int n_in,
                              void* d_out, int out_size, void* d_ws, size_t ws_size,
                              hipStream_t stream) {
    const float* x = (const float*)d_in[0];
    float* out = (float*)d_out;

    // out_size = 50176*R + n_out,  n_out <= 512 < 50176  -> unique split
    const int plane = BATCH * HW;               // 50176
    const int R     = out_size / plane;         // total replicated channels

    float* partial = (float*)d_ws;              // CH*NQ floats (8 KB)

    absmax_kernel<<<dim3(CH, NQ), 256, 0, stream>>>(x, partial);
    if (R > 0) {
        gather_kernel<<<dim3(R), 256, 0, stream>>>(
            x, partial, out, out + (size_t)R * plane, R);
    }
}